// Round 1
// baseline (2643.293 us; speedup 1.0000x reference)
//
#include <hip/hip_runtime.h>
#include <math.h>

// LatentDecoder on MI355X. All f32. Rotations R eliminated (orthogonal, cancel
// around per-channel gates). Per-edge linear maps commuted to per-node + gather.
// Requires ws_size >= ~139MB (checked; returns leaving d_out poisoned if not).

#define NN 8192
#define KK 30
#define NE (NN*KK)      // 245760
#define EPSF 1e-7f

// ---------------- workspace layout (bytes) ----------------
static const size_t O_SRC = 0;                  // int [NN*30]
static const size_t O_XS  = 1ull<<20;           // float[NN] x of CA
static const size_t O_YS  = O_XS + (size_t)NN*4;
static const size_t O_ZS  = O_XS + (size_t)NN*8;
static const size_t O_BBE = 2ull<<20;           // float[NN*4*26] bb embedding
static const size_t O_RES = 6ull<<20;           // float[NN*4*64]
static const size_t O_P   = 15ull<<20;          // float[NN*4*32]
static const size_t O_EF  = 20ull<<20;          // float[NE*32]
// layer-phase scratch:
static const size_t O_NF  = 52ull<<20;          // float[NN*80]  [A1|A2|V0]
static const size_t O_V1  = 56ull<<20;          // float[NN*3*64]
static const size_t O_O   = 63ull<<20;          // float[NN*4*64] (also U)
static const size_t O_T   = 72ull<<20;          // float[NN*4*64]
static const size_t O_EE  = 81ull<<20;          // float[NN*64]  [E1|E2]
static const size_t O_EW  = 84ull<<20;          // float[NE*40]  [alog|edgepart]
// so3 phases (time-disjoint aliases of the above region):
static const size_t O_M0  = 52ull<<20;          // float[NN*91] max
static const size_t O_M1  = 56ull<<20;          // float[NN*3*91] max
static const size_t O_ATM = 65ull<<20;          // float[NN*4*91]
static const size_t O_H   = 77ull<<20;          // float[61440*64] gate hidden chunk
static const size_t O_G   = 93ull<<20;          // float[61440*182] gate out chunk
static const size_t O_BRP = 138ull<<20;         // repacked weights (<128KB)
static const size_t WS_NEEDED = O_BRP + (1ull<<17);

// ---------------- small device helpers ----------------
__device__ __forceinline__ float nn0(float v){ return (v != v) ? 0.f : v; }
__device__ __forceinline__ void norm3(float& x, float& y, float& z){
  float s = sqrtf(x*x + y*y + z*z + EPSF);
  x /= s; y /= s; z /= s;
}

// ---------------- prep: extract CA, build bbemb rows 1..3 + zeros ----------------
__global__ void k_prep(const float* __restrict__ bb, float* __restrict__ xs,
                       float* __restrict__ ys, float* __restrict__ zs,
                       float* __restrict__ bbe){
  int n = blockIdx.x*blockDim.x + threadIdx.x;
  if (n >= NN) return;
  const float* bn = bb + (size_t)n*12;
  float a0x=bn[0],a0y=bn[1],a0z=bn[2];
  float cax=bn[3],cay=bn[4],caz=bn[5];
  float a2x=bn[6],a2y=bn[7],a2z=bn[8];
  float a3x=bn[9],a3y=bn[10],a3z=bn[11];
  xs[n]=cax; ys[n]=cay; zs[n]=caz;
  float v[7][3];
  v[0][0]=a0x-cax; v[0][1]=a0y-cay; v[0][2]=a0z-caz;
  v[1][0]=0.f;     v[1][1]=0.f;     v[1][2]=0.f;
  v[2][0]=a2x-cax; v[2][1]=a2y-cay; v[2][2]=a2z-caz;
  v[3][0]=a3x-cax; v[3][1]=a3y-cay; v[3][2]=a3z-caz;
  // forward / backward CA orientations
  if (n < NN-1){
    float fx=bb[(size_t)(n+1)*12+3]-cax, fy=bb[(size_t)(n+1)*12+4]-cay, fz=bb[(size_t)(n+1)*12+5]-caz;
    norm3(fx,fy,fz); v[4][0]=fx; v[4][1]=fy; v[4][2]=fz;
  } else { v[4][0]=v[4][1]=v[4][2]=0.f; }
  if (n > 0){
    float gx=bb[(size_t)(n-1)*12+3]-cax, gy=bb[(size_t)(n-1)*12+4]-cay, gz=bb[(size_t)(n-1)*12+5]-caz;
    norm3(gx,gy,gz); v[5][0]=gx; v[5][1]=gy; v[5][2]=gz;
  } else { v[5][0]=v[5][1]=v[5][2]=0.f; }
  // virtual CB
  {
    float bx=cax-a0x, by=cay-a0y, bz=caz-a0z;
    float cx=a2x-cax, cy=a2y-cay, cz=a2z-caz;
    float ax = by*cz - bz*cy, ay = bz*cx - bx*cz, az = bx*cy - by*cx;
    v[6][0] = -0.58273431f*ax + 0.56802827f*bx - 0.54067466f*cx;
    v[6][1] = -0.58273431f*ay + 0.56802827f*by - 0.54067466f*cy;
    v[6][2] = -0.58273431f*az + 0.56802827f*bz - 0.54067466f*cz;
  }
  float* be = bbe + (size_t)n*104;
  #pragma unroll
  for (int c=6;c<26;++c) be[c]=0.f;           // scal tail zeros (dihedrals fill 0..5)
  #pragma unroll
  for (int s=0;s<3;++s){
    float* br = be + 26*(1+s);
    #pragma unroll
    for (int c=0;c<26;++c) br[c] = (c<7) ? nn0(v[c][s]) : 0.f;
  }
}

// ---------------- dihedrals -> bbemb row0 cols 0..5 ----------------
__global__ void k_dihed(const float* __restrict__ bb, float* __restrict__ bbe){
  int t = blockIdx.x*blockDim.x + threadIdx.x;
  if (t >= 3*NN) return;
  float cD = 1.f, sD = 0.f;
  if (t >= 1 && t < 3*NN-2){
    int i = t-1;
    float p[4][3];
    #pragma unroll
    for (int m=0;m<4;++m){
      int a = i+m; int rn = a/3, ra = a - rn*3;
      const float* q = bb + (size_t)(rn*4 + ra)*3;
      p[m][0]=q[0]; p[m][1]=q[1]; p[m][2]=q[2];
    }
    float u2x=p[1][0]-p[0][0], u2y=p[1][1]-p[0][1], u2z=p[1][2]-p[0][2];
    float u1x=p[2][0]-p[1][0], u1y=p[2][1]-p[1][1], u1z=p[2][2]-p[1][2];
    float u0x=p[3][0]-p[2][0], u0y=p[3][1]-p[2][1], u0z=p[3][2]-p[2][2];
    norm3(u2x,u2y,u2z); norm3(u1x,u1y,u1z); norm3(u0x,u0y,u0z);
    float n2x=u2y*u1z-u2z*u1y, n2y=u2z*u1x-u2x*u1z, n2z=u2x*u1y-u2y*u1x;
    float n1x=u1y*u0z-u1z*u0y, n1y=u1z*u0x-u1x*u0z, n1z=u1x*u0y-u1y*u0x;
    norm3(n2x,n2y,n2z); norm3(n1x,n1y,n1z);
    float cosD = n2x*n1x + n2y*n1y + n2z*n1z;
    const float lo = (float)(-1.0 + 1e-7), hi = (float)(1.0 - 1e-7);
    cosD = fminf(fmaxf(cosD, lo), hi);
    float sg = u2x*n1x + u2y*n1y + u2z*n1z;
    float sgn = (sg > 0.f) ? 1.f : ((sg < 0.f) ? -1.f : 0.f);
    float D = sgn * acosf(cosD);
    cD = cosf(D); sD = sinf(D);
  }
  int n = t/3, col = t - n*3;
  bbe[(size_t)n*104 + col] = cD;
  bbe[(size_t)n*104 + 3 + col] = sD;
}

// ---------------- KNN: wave per query, shared LDS top-30 ----------------
__global__ __launch_bounds__(256) void k_knn(const float* __restrict__ xs,
        const float* __restrict__ ys, const float* __restrict__ zs, int* __restrict__ src){
  __shared__ float sd[4][32];
  __shared__ int   si[4][32];
  int w = threadIdx.x >> 6, lane = threadIdx.x & 63;
  int n = blockIdx.x*4 + w;
  float qx = xs[n], qy = ys[n], qz = zs[n];
  if (lane < 32){ sd[w][lane] = INFINITY; si[w][lane] = 0; }
  float thr = INFINITY;
  for (int s = 0; s < NN/64; ++s){
    int j = s*64 + lane;
    float dx = __fsub_rn(qx, xs[j]);
    float dy = __fsub_rn(qy, ys[j]);
    float dz = __fsub_rn(qz, zs[j]);
    float d2 = __fadd_rn(__fadd_rn(__fmul_rn(dx,dx),__fmul_rn(dy,dy)),__fmul_rn(dz,dz));
    if (j == n) d2 = INFINITY;
    unsigned long long bal = __ballot(d2 < thr);
    if (bal){
      while (bal){
        int b = __ffsll((unsigned long long)bal) - 1;
        bal &= bal - 1ull;
        float vd = __shfl(d2, b);
        int vj = s*64 + b;
        float dl = 0.f; int il = 0; bool keep = true;
        if (lane < 30){ dl = sd[w][lane]; il = si[w][lane]; keep = (dl <= vd); }
        unsigned long long km = __ballot(lane < 30 && keep);
        int pos = __popcll(km);
        if (lane < 30 && !keep){ sd[w][lane+1] = dl; si[w][lane+1] = il; }
        if (lane == pos){ sd[w][lane] = vd; si[w][lane] = vj; }
      }
      thr = sd[w][29];
    }
  }
  if (lane < 30) src[(size_t)n*KK + lane] = si[w][lane];
}

// ---------------- edge features: rbf(16) + pos_emb(16) ----------------
__global__ void k_edgefeat(const int* __restrict__ src, const float* __restrict__ xs,
        const float* __restrict__ ys, const float* __restrict__ zs, float* __restrict__ ef){
  int e = blockIdx.x*blockDim.x + threadIdx.x;
  if (e >= NE) return;
  int n = e / KK;
  int j = src[e];
  float vx = xs[j]-xs[n], vy = ys[j]-ys[n], vz = zs[j]-zs[n];
  float dist = sqrtf(vx*vx + vy*vy + vz*vz + EPSF);
  float* o = ef + (size_t)e*32;
  #pragma unroll
  for (int m=0;m<16;++m){
    float mu = (float)m * (20.f/15.f);
    float q = (dist - mu) / 1.25f;
    o[m] = expf(-q*q);
  }
  float d = (float)(j - n);
  const float Cf = -0.5756462732485115f;   // -ln(1e4)/16
  #pragma unroll
  for (int fi=0; fi<8; ++fi){
    float fr = expf((float)(2*fi) * Cf);
    float ang = d * fr;
    o[16+fi] = cosf(ang);
    o[24+fi] = sinf(ang);
  }
}

// ---------------- generic f32 GEMM: C[M,Nc] = act(A@B + bias) (+C if beta) ----------------
// A row r -> A + (r/arpg)*agst + (r%arpg)*arst + aoff  (arpg in {1,3})
template<int K, int ACT>
__global__ __launch_bounds__(256) void k_gemm(const float* __restrict__ A,
        const float* __restrict__ B, const float* __restrict__ bias, float* __restrict__ C,
        int M, int Nc, int arpg, int agst, int arst, int aoff, int beta){
  __shared__ float As[64*(K+1)];
  __shared__ alignas(16) float Bs[K*64];
  int tid = threadIdx.x, tm = blockIdx.x, tn = blockIdx.y;
  for (int i = tid; i < K*64; i += 256){
    int kk = i >> 6, cl = i & 63;
    int c = tn*64 + cl;
    Bs[i] = (c < Nc) ? B[kk*Nc + c] : 0.f;
  }
  for (int i = tid; i < 64*K; i += 256){
    int rl = i / K, kk = i - rl*K;
    int r = tm*64 + rl;
    float v = 0.f;
    if (r < M){
      const float* ap;
      if (arpg == 1) ap = A + (size_t)r*agst + aoff;
      else { int g = r/3; int wr = r - g*3; ap = A + (size_t)g*agst + wr*arst + aoff; }
      v = ap[kk];
    }
    As[rl*(K+1) + kk] = v;
  }
  __syncthreads();
  int tx = tid & 15, ty = tid >> 4;
  float acc[4][4] = {};
  for (int kk = 0; kk < K; ++kk){
    float4 b4 = *reinterpret_cast<const float4*>(&Bs[kk*64 + tx*4]);
    #pragma unroll
    for (int rr = 0; rr < 4; ++rr){
      float a = As[(ty*4+rr)*(K+1) + kk];
      acc[rr][0] += a*b4.x; acc[rr][1] += a*b4.y; acc[rr][2] += a*b4.z; acc[rr][3] += a*b4.w;
    }
  }
  #pragma unroll
  for (int rr = 0; rr < 4; ++rr){
    int r = tm*64 + ty*4 + rr;
    if (r >= M) continue;
    #pragma unroll
    for (int cc = 0; cc < 4; ++cc){
      int c = tn*64 + tx*4 + cc;
      if (c >= Nc) continue;
      float v = acc[rr][cc];
      if (bias) v += bias[c];
      if (ACT == 1) v = v / (1.f + expf(-v)) ;   // silu = x*sigmoid(x) = x/(1+e^-x)
      size_t ci = (size_t)r*Nc + c;
      if (beta) v += C[ci];
      C[ci] = v;
    }
  }
}

// ---------------- fused attention: logits+softmax+gather-weighted sums ----------------
// NF: [A1(8)|A2(8)|V0(64)] per node; V1: (N,3,64); LG: per-edge logit partial (stride lgs)
__global__ __launch_bounds__(256) void k_attn(const int* __restrict__ src,
        const float* __restrict__ NF, const float* __restrict__ V1,
        const float* __restrict__ LG, int lgs, float* __restrict__ o){
  int w = threadIdx.x >> 6, lane = threadIdx.x & 63;
  int n = blockIdx.x*4 + w;
  int h = lane >> 3;
  const int* sk = src + (size_t)n*KK;
  int myj = (lane < KK) ? sk[lane] : 0;
  float a2 = NF[(size_t)n*80 + 8 + h];
  float m = -INFINITY, s = 0.f, o0=0.f, o1=0.f, o2=0.f, o3=0.f;
  for (int k = 0; k < KK; ++k){
    int j = __shfl(myj, k);
    float l = LG[((size_t)n*KK + k)*lgs + h] + NF[(size_t)j*80 + h] + a2;
    l = (l >= 0.f) ? l : 0.2f*l;
    float mn = fmaxf(m, l);
    float f = expf(m - mn);
    float pp = expf(l - mn);
    s = s*f + pp;
    const float* v1p = V1 + (size_t)j*192;
    o0 = o0*f + pp*NF[(size_t)j*80 + 16 + lane];
    o1 = o1*f + pp*v1p[lane];
    o2 = o2*f + pp*v1p[64+lane];
    o3 = o3*f + pp*v1p[128+lane];
    m = mn;
  }
  float inv = 1.f/s;
  float* op = o + (size_t)n*256;
  op[lane] = o0*inv; op[64+lane] = o1*inv; op[128+lane] = o2*inv; op[192+lane] = o3*inv;
}

// ---------------- so3 gather-aggregate ----------------
template<int C>
__global__ void k_so3agg(const int* __restrict__ src, const float* __restrict__ G,
        const float* __restrict__ M0, const float* __restrict__ M1, float* __restrict__ out,
        int n0, int nodes, int nstr, int sstr){
  int t = blockIdx.x*blockDim.x + threadIdx.x;
  if (t >= nodes*C) return;
  int nl = t / C, c = t - nl*C;
  int n = n0 + nl;
  const int* sk = src + (size_t)n*KK;
  const float* gb = G + (size_t)nl*KK*2*C;
  float a0=0.f,a1=0.f,a2=0.f,a3=0.f;
  for (int k=0;k<KK;++k){
    int j = sk[k];
    float g0 = gb[k*2*C + c], g1 = gb[k*2*C + C + c];
    a0 += g0 * M0[(size_t)j*C + c];
    const float* m1p = M1 + (size_t)j*3*C;
    a1 += g1*m1p[c]; a2 += g1*m1p[C+c]; a3 += g1*m1p[2*C+c];
  }
  const float SQ = 5.477225575051661f;  // sqrt(30)
  float* ob = out + (size_t)n*nstr + c;
  ob[0] = a0/SQ; ob[sstr] = a1/SQ; ob[2*sstr] = a2/SQ; ob[3*sstr] = a3/SQ;
}

// ---------------- latent copy into res cols 32..63 ----------------
__global__ void k_lat(const float* __restrict__ latent, float* __restrict__ res){
  int t = blockIdx.x*blockDim.x + threadIdx.x;
  if (t >= NN*128) return;
  int n = t >> 7, rc = t & 127, s = rc >> 5, c = rc & 31;
  res[(size_t)n*256 + s*64 + 32 + c] = latent[t];
}

// ---------------- swiglu-style FFN gate ----------------
template<int C>
__global__ void k_swiglu(const float* __restrict__ T, float* __restrict__ U){
  int t = blockIdx.x*blockDim.x + threadIdx.x;
  if (t >= NN*C) return;
  int n = t / C, c = t - n*C;
  const float* tp = T + (size_t)n*4*C + c;
  float t0 = tp[0];
  float g = 1.f/(1.f + expf(-t0));
  float* up = U + (size_t)n*4*C + c;
  up[0]   = t0*g;
  up[C]   = tp[C]*g;
  up[2*C] = tp[2*C]*g;
  up[3*C] = tp[3*C]*g;
}

// ---------------- edge feature update ----------------
__global__ void k_edgeout(const int* __restrict__ src, const float* __restrict__ EW,
        const float* __restrict__ EE, const float* __restrict__ ebv, float* __restrict__ ef){
  int t = blockIdx.x*blockDim.x + threadIdx.x;
  if (t >= NE*8) return;
  int e = t >> 3, q = t & 7, c = q*4;
  int n = e / KK;
  int j = src[e];
  float4 w4 = *(const float4*)(EW + (size_t)e*40 + 8 + c);
  float4 e1 = *(const float4*)(EE + (size_t)j*64 + c);
  float4 e2 = *(const float4*)(EE + (size_t)n*64 + 32 + c);
  float4 b4 = *(const float4*)(ebv + c);
  float4 r;
  r.x = tanhf(w4.x + e1.x + e2.x + b4.x);
  r.y = tanhf(w4.y + e1.y + e2.y + b4.y);
  r.z = tanhf(w4.z + e1.z + e2.z + b4.z);
  r.w = tanhf(w4.w + e1.w + e2.w + b4.w);
  *(float4*)(ef + (size_t)e*32 + c) = r;
}

// ---------------- per-layer weight repack ----------------
// Bnode(64,80)=[Wa_src|Wa_dst|Wv0], Bedge(32,40)=[Wa_e|eW_e], Bee(64,64)=[eW_src|eW_dst]
__global__ void k_repack(const float* __restrict__ Wa, const float* __restrict__ Wv0,
        const float* __restrict__ eW, float* __restrict__ Bnode, float* __restrict__ Bedge,
        float* __restrict__ Bee){
  int t = blockIdx.x*blockDim.x + threadIdx.x;
  if (t < 5120){
    int k = t/80, c = t - k*80;
    Bnode[t] = (c<8) ? Wa[k*8+c] : ((c<16) ? Wa[(64+k)*8 + (c-8)] : Wv0[k*64 + (c-16)]);
  } else if (t < 6400){
    int i = t - 5120; int k = i/40, c = i - k*40;
    Bedge[i] = (c<8) ? Wa[(128+k)*8 + c] : eW[(128+k)*32 + (c-8)];
  } else if (t < 10496){
    int i = t - 6400; int k = i >> 6, c = i & 63;
    Bee[i] = (c<32) ? eW[k*32 + c] : eW[(64+k)*32 + (c-32)];
  }
}

// ---------------- head: LN + seq logits + transpose decoded ----------------
__global__ __launch_bounds__(128) void k_head(const float* __restrict__ atoms,
        const float* __restrict__ ln_g, const float* __restrict__ ln_b,
        const float* __restrict__ W_seq, const float* __restrict__ b_seq, float* __restrict__ out){
  __shared__ float red[128];
  __shared__ float nrm[91];
  __shared__ float lg[20];
  int n = blockIdx.x, t = threadIdx.x;
  const float* inv = atoms + (size_t)n*364;
  float x = (t < 91) ? inv[t] : 0.f;
  red[t] = x; __syncthreads();
  for (int off=64; off>=1; off>>=1){ if (t<off) red[t]+=red[t+off]; __syncthreads(); }
  float mu = red[0] / 91.f;
  __syncthreads();
  float d = x - mu;
  red[t] = (t<91) ? d*d : 0.f; __syncthreads();
  for (int off=64; off>=1; off>>=1){ if (t<off) red[t]+=red[t+off]; __syncthreads(); }
  float var = red[0] / 91.f;
  __syncthreads();
  if (t < 91) nrm[t] = (x - mu)/sqrtf(var + 1e-5f) * ln_g[t] + ln_b[t];
  __syncthreads();
  if (t < 20){
    float acc = b_seq[t];
    for (int c=0;c<91;++c) acc += nrm[c]*W_seq[c*20+t];
    lg[t] = acc;
  }
  __syncthreads();
  if (t == 0){
    float mx = lg[0];
    for (int i=1;i<20;++i) mx = fmaxf(mx, lg[i]);
    float s = 0.f;
    for (int i=0;i<20;++i) s += expf(lg[i]-mx);
    red[0] = mx + logf(s);
  }
  __syncthreads();
  float lse = red[0];
  if (t < 20) out[(size_t)NN*273 + (size_t)n*20 + t] = lg[t] - lse;
  for (int idx = t; idx < 273; idx += 128){
    int c = idx/3, i = idx - c*3;
    out[(size_t)n*273 + idx] = atoms[(size_t)n*364 + (1+i)*91 + c];
  }
}

// ---------------- host dispatch ----------------
static void gemm(hipStream_t st, int K, int act, const float* A, const float* B,
                 const float* bias, float* C, int M, int Nc,
                 int arpg, int agst, int arst, int aoff, int beta){
  dim3 g((M+63)/64, (Nc+63)/64), b(256);
  if (K == 26){
    k_gemm<26,0><<<g,b,0,st>>>(A,B,bias,C,M,Nc,arpg,agst,arst,aoff,beta);
  } else if (K == 32){
    if (act) k_gemm<32,1><<<g,b,0,st>>>(A,B,bias,C,M,Nc,arpg,agst,arst,aoff,beta);
    else     k_gemm<32,0><<<g,b,0,st>>>(A,B,bias,C,M,Nc,arpg,agst,arst,aoff,beta);
  } else {
    if (act) k_gemm<64,1><<<g,b,0,st>>>(A,B,bias,C,M,Nc,arpg,agst,arst,aoff,beta);
    else     k_gemm<64,0><<<g,b,0,st>>>(A,B,bias,C,M,Nc,arpg,agst,arst,aoff,beta);
  }
}

extern "C" void kernel_launch(void* const* d_in, const int* in_sizes, int n_in,
                              void* d_out, int out_size, void* d_ws, size_t ws_size,
                              hipStream_t stream){
  (void)in_sizes; (void)n_in; (void)out_size;
  if (ws_size < WS_NEEDED) return;  // insufficient scratch: leave d_out poisoned (fails cleanly)

  const float* bb      = (const float*)d_in[0];
  const float* latent  = (const float*)d_in[2];
  const float* eb_Wrad = (const float*)d_in[3];
  const float* eb_brad = (const float*)d_in[4];
  const float* eb_Wgate= (const float*)d_in[5];
  const float* eb_W0   = (const float*)d_in[6];
  const float* eb_W1   = (const float*)d_in[7];
  const float* t_Walpha= (const float*)d_in[8];
  const float* t_Wv0   = (const float*)d_in[9];
  const float* t_Wv1   = (const float*)d_in[10];
  const float* t_Wo    = (const float*)d_in[11];
  const float* t_Wf1   = (const float*)d_in[12];
  const float* t_Wf2   = (const float*)d_in[13];
  const float* e_W     = (const float*)d_in[14];
  const float* e_b     = (const float*)d_in[15];
  const float* p_Walpha= (const float*)d_in[16];
  const float* p_Wv0   = (const float*)d_in[17];
  const float* p_Wv1   = (const float*)d_in[18];
  const float* p_Wo    = (const float*)d_in[19];
  const float* p_Wf1   = (const float*)d_in[20];
  const float* p_Wf2   = (const float*)d_in[21];
  const float* oa_Wrad = (const float*)d_in[22];
  const float* oa_brad = (const float*)d_in[23];
  const float* oa_Wgate= (const float*)d_in[24];
  const float* oa_W0   = (const float*)d_in[25];
  const float* oa_W1   = (const float*)d_in[26];
  const float* ln_g    = (const float*)d_in[27];
  const float* ln_b    = (const float*)d_in[28];
  const float* W_seq   = (const float*)d_in[29];
  const float* b_seq   = (const float*)d_in[30];

  char* w = (char*)d_ws;
  int*   src = (int*)  (w + O_SRC);
  float* xs  = (float*)(w + O_XS);
  float* ys  = (float*)(w + O_YS);
  float* zs  = (float*)(w + O_ZS);
  float* bbe = (float*)(w + O_BBE);
  float* res = (float*)(w + O_RES);
  float* p   = (float*)(w + O_P);
  float* ef  = (float*)(w + O_EF);
  float* NF  = (float*)(w + O_NF);
  float* V1  = (float*)(w + O_V1);
  float* o   = (float*)(w + O_O);
  float* T   = (float*)(w + O_T);
  float* EE  = (float*)(w + O_EE);
  float* EW  = (float*)(w + O_EW);
  float* M0  = (float*)(w + O_M0);
  float* M1  = (float*)(w + O_M1);
  float* atm = (float*)(w + O_ATM);
  float* H   = (float*)(w + O_H);
  float* G   = (float*)(w + O_G);
  float* Bnode = (float*)(w + O_BRP);
  float* Bedge = (float*)(w + O_BRP + 32768);
  float* Bee   = (float*)(w + O_BRP + 65536);

  // ---- geometry ----
  k_prep <<<(NN+255)/256, 256, 0, stream>>>(bb, xs, ys, zs, bbe);
  k_dihed<<<(3*NN+255)/256, 256, 0, stream>>>(bb, bbe);
  k_knn  <<<NN/4, 256, 0, stream>>>(xs, ys, zs, src);
  k_edgefeat<<<(NE+255)/256, 256, 0, stream>>>(src, xs, ys, zs, ef);

  // ---- eb so3_conv -> res[:,:,0:32] ----
  gemm(stream, 26,0, bbe, eb_W0, nullptr, M0, NN,   32, 1,104, 0, 0, 0);
  gemm(stream, 26,0, bbe, eb_W1, nullptr, M1, 3*NN, 32, 3,104,26,26, 0);
  for (int cz=0; cz<4; ++cz){
    int n0 = cz*2048, me = 2048*KK;
    gemm(stream, 32,1, ef + (size_t)n0*KK*32, eb_Wrad, eb_brad, H, me, 64, 1,32,0,0, 0);
    gemm(stream, 64,0, H, eb_Wgate, nullptr, G, me, 64, 1,64,0,0, 0);
    k_so3agg<32><<<(2048*32+255)/256, 256, 0, stream>>>(src, G, M0, M1, res, n0, 2048, 256, 64);
  }
  k_lat<<<(NN*128+255)/256, 256, 0, stream>>>(latent, res);

  // ---- transformer layers ----
  for (int L=0; L<4; ++L){
    const float* Wa  = t_Walpha + (size_t)L*160*8;
    const float* Wv0 = t_Wv0 + (size_t)L*64*64;
    const float* Wv1 = t_Wv1 + (size_t)L*64*64;
    const float* Wo  = t_Wo  + (size_t)L*64*64;
    const float* Wf1 = t_Wf1 + (size_t)L*64*64;
    const float* Wf2 = t_Wf2 + (size_t)L*64*64;
    const float* eWl = e_W   + (size_t)L*160*32;
    const float* ebl = e_b   + (size_t)L*32;
    k_repack<<<41, 256, 0, stream>>>(Wa, Wv0, eWl, Bnode, Bedge, Bee);
    gemm(stream, 64,0, res, Bnode, nullptr, NF, NN,   80, 1,256, 0, 0, 0);
    gemm(stream, 64,0, res, Wv1,   nullptr, V1, 3*NN, 64, 3,256,64,64, 0);
    gemm(stream, 32,0, ef,  Bedge, nullptr, EW, NE,   40, 1, 32, 0, 0, 0);
    k_attn<<<NN/4, 256, 0, stream>>>(src, NF, V1, EW, 40, o);
    gemm(stream, 64,0, o,   Wo,  nullptr, res, 4*NN, 64, 1,64,0,0, 1);
    gemm(stream, 64,0, res, Wf1, nullptr, T,   4*NN, 64, 1,64,0,0, 0);
    k_swiglu<64><<<(NN*64+255)/256, 256, 0, stream>>>(T, o);
    gemm(stream, 64,0, o,   Wf2, nullptr, res, 4*NN, 64, 1,64,0,0, 1);
    gemm(stream, 64,0, res, Bee, nullptr, EE,  NN,   64, 1,256,0,0, 0);
    k_edgeout<<<(NE*8+255)/256, 256, 0, stream>>>(src, EW, EE, ebl, ef);
  }

  // ---- p = attn(res) + ffn ----
  k_repack<<<41, 256, 0, stream>>>(p_Walpha, p_Wv0, e_W + (size_t)3*160*32, Bnode, Bedge, Bee);
  gemm(stream, 64,0, res, Bnode, nullptr, NF, NN,   80, 1,256, 0, 0, 0);
  gemm(stream, 64,0, res, p_Wv1, nullptr, V1, 3*NN, 64, 3,256,64,64, 0);
  gemm(stream, 32,0, ef,  p_Walpha + 128*8, nullptr, EW, NE, 8, 1,32,0,0, 0);
  k_attn<<<NN/4, 256, 0, stream>>>(src, NF, V1, EW, 8, o);
  gemm(stream, 64,0, o, p_Wo,  nullptr, p, 4*NN, 32, 1,64,0,0, 0);
  gemm(stream, 32,0, p, p_Wf1, nullptr, T, 4*NN, 32, 1,32,0,0, 0);
  k_swiglu<32><<<(NN*32+255)/256, 256, 0, stream>>>(T, o);
  gemm(stream, 32,0, o, p_Wf2, nullptr, p, 4*NN, 32, 1,32,0,0, 1);

  // ---- oa so3_conv -> atoms ----
  gemm(stream, 32,0, p, oa_W0, nullptr, M0, NN,   91, 1,128, 0, 0, 0);
  gemm(stream, 32,0, p, oa_W1, nullptr, M1, 3*NN, 91, 3,128,32,32, 0);
  for (int cz=0; cz<4; ++cz){
    int n0 = cz*2048, me = 2048*KK;
    gemm(stream, 32,1, ef + (size_t)n0*KK*32, oa_Wrad, oa_brad, H, me, 64, 1,32,0,0, 0);
    gemm(stream, 64,0, H, oa_Wgate, nullptr, G, me, 182, 1,64,0,0, 0);
    k_so3agg<91><<<(2048*91+255)/256, 256, 0, stream>>>(src, G, M0, M1, atm, n0, 2048, 364, 91);
  }

  // ---- head ----
  k_head<<<NN, 128, 0, stream>>>(atm, ln_g, ln_b, W_seq, b_seq, (float*)d_out);
}

// Round 2
// 2155.851 us; speedup vs baseline: 1.2261x; 1.2261x over previous
//
#include <hip/hip_runtime.h>
#include <math.h>

// LatentDecoder on MI355X. All f32. Rotations R eliminated (orthogonal, cancel
// around per-channel gates). Per-edge linear maps commuted to per-node + gather.
// Requires ws_size >= ~139MB (checked; returns leaving d_out poisoned if not).
// R1: KNN rewritten — window-seeded threshold via wave bitonic sort, then
//     thresholded full scan (exact). Was 543us (ballot-insert serialization).

#define NN 8192
#define KK 30
#define NE (NN*KK)      // 245760
#define EPSF 1e-7f

// ---------------- workspace layout (bytes) ----------------
static const size_t O_SRC = 0;                  // int [NN*30]
static const size_t O_XS  = 1ull<<20;           // float[NN] x of CA
static const size_t O_YS  = O_XS + (size_t)NN*4;
static const size_t O_ZS  = O_XS + (size_t)NN*8;
static const size_t O_BBE = 2ull<<20;           // float[NN*4*26] bb embedding
static const size_t O_RES = 6ull<<20;           // float[NN*4*64]
static const size_t O_P   = 15ull<<20;          // float[NN*4*32]
static const size_t O_EF  = 20ull<<20;          // float[NE*32]
// layer-phase scratch:
static const size_t O_NF  = 52ull<<20;          // float[NN*80]  [A1|A2|V0]
static const size_t O_V1  = 56ull<<20;          // float[NN*3*64]
static const size_t O_O   = 63ull<<20;          // float[NN*4*64] (also U)
static const size_t O_T   = 72ull<<20;          // float[NN*4*64]
static const size_t O_EE  = 81ull<<20;          // float[NN*64]  [E1|E2]
static const size_t O_EW  = 84ull<<20;          // float[NE*40]  [alog|edgepart]
// so3 phases (time-disjoint aliases of the above region):
static const size_t O_M0  = 52ull<<20;          // float[NN*91] max
static const size_t O_M1  = 56ull<<20;          // float[NN*3*91] max
static const size_t O_ATM = 65ull<<20;          // float[NN*4*91]
static const size_t O_H   = 77ull<<20;          // float[61440*64] gate hidden chunk
static const size_t O_G   = 93ull<<20;          // float[61440*182] gate out chunk
static const size_t O_BRP = 138ull<<20;         // repacked weights (<128KB)
static const size_t WS_NEEDED = O_BRP + (1ull<<17);

// ---------------- small device helpers ----------------
__device__ __forceinline__ float nn0(float v){ return (v != v) ? 0.f : v; }
__device__ __forceinline__ void norm3(float& x, float& y, float& z){
  float s = sqrtf(x*x + y*y + z*z + EPSF);
  x /= s; y /= s; z /= s;
}

// ---------------- prep: extract CA, build bbemb rows 1..3 + zeros ----------------
__global__ void k_prep(const float* __restrict__ bb, float* __restrict__ xs,
                       float* __restrict__ ys, float* __restrict__ zs,
                       float* __restrict__ bbe){
  int n = blockIdx.x*blockDim.x + threadIdx.x;
  if (n >= NN) return;
  const float* bn = bb + (size_t)n*12;
  float a0x=bn[0],a0y=bn[1],a0z=bn[2];
  float cax=bn[3],cay=bn[4],caz=bn[5];
  float a2x=bn[6],a2y=bn[7],a2z=bn[8];
  float a3x=bn[9],a3y=bn[10],a3z=bn[11];
  xs[n]=cax; ys[n]=cay; zs[n]=caz;
  float v[7][3];
  v[0][0]=a0x-cax; v[0][1]=a0y-cay; v[0][2]=a0z-caz;
  v[1][0]=0.f;     v[1][1]=0.f;     v[1][2]=0.f;
  v[2][0]=a2x-cax; v[2][1]=a2y-cay; v[2][2]=a2z-caz;
  v[3][0]=a3x-cax; v[3][1]=a3y-cay; v[3][2]=a3z-caz;
  // forward / backward CA orientations
  if (n < NN-1){
    float fx=bb[(size_t)(n+1)*12+3]-cax, fy=bb[(size_t)(n+1)*12+4]-cay, fz=bb[(size_t)(n+1)*12+5]-caz;
    norm3(fx,fy,fz); v[4][0]=fx; v[4][1]=fy; v[4][2]=fz;
  } else { v[4][0]=v[4][1]=v[4][2]=0.f; }
  if (n > 0){
    float gx=bb[(size_t)(n-1)*12+3]-cax, gy=bb[(size_t)(n-1)*12+4]-cay, gz=bb[(size_t)(n-1)*12+5]-caz;
    norm3(gx,gy,gz); v[5][0]=gx; v[5][1]=gy; v[5][2]=gz;
  } else { v[5][0]=v[5][1]=v[5][2]=0.f; }
  // virtual CB
  {
    float bx=cax-a0x, by=cay-a0y, bz=caz-a0z;
    float cx=a2x-cax, cy=a2y-cay, cz=a2z-caz;
    float ax = by*cz - bz*cy, ay = bz*cx - bx*cz, az = bx*cy - by*cx;
    v[6][0] = -0.58273431f*ax + 0.56802827f*bx - 0.54067466f*cx;
    v[6][1] = -0.58273431f*ay + 0.56802827f*by - 0.54067466f*cy;
    v[6][2] = -0.58273431f*az + 0.56802827f*bz - 0.54067466f*cz;
  }
  float* be = bbe + (size_t)n*104;
  #pragma unroll
  for (int c=6;c<26;++c) be[c]=0.f;           // scal tail zeros (dihedrals fill 0..5)
  #pragma unroll
  for (int s=0;s<3;++s){
    float* br = be + 26*(1+s);
    #pragma unroll
    for (int c=0;c<26;++c) br[c] = (c<7) ? nn0(v[c][s]) : 0.f;
  }
}

// ---------------- dihedrals -> bbemb row0 cols 0..5 ----------------
__global__ void k_dihed(const float* __restrict__ bb, float* __restrict__ bbe){
  int t = blockIdx.x*blockDim.x + threadIdx.x;
  if (t >= 3*NN) return;
  float cD = 1.f, sD = 0.f;
  if (t >= 1 && t < 3*NN-2){
    int i = t-1;
    float p[4][3];
    #pragma unroll
    for (int m=0;m<4;++m){
      int a = i+m; int rn = a/3, ra = a - rn*3;
      const float* q = bb + (size_t)(rn*4 + ra)*3;
      p[m][0]=q[0]; p[m][1]=q[1]; p[m][2]=q[2];
    }
    float u2x=p[1][0]-p[0][0], u2y=p[1][1]-p[0][1], u2z=p[1][2]-p[0][2];
    float u1x=p[2][0]-p[1][0], u1y=p[2][1]-p[1][1], u1z=p[2][2]-p[1][2];
    float u0x=p[3][0]-p[2][0], u0y=p[3][1]-p[2][1], u0z=p[3][2]-p[2][2];
    norm3(u2x,u2y,u2z); norm3(u1x,u1y,u1z); norm3(u0x,u0y,u0z);
    float n2x=u2y*u1z-u2z*u1y, n2y=u2z*u1x-u2x*u1z, n2z=u2x*u1y-u2y*u1x;
    float n1x=u1y*u0z-u1z*u0y, n1y=u1z*u0x-u1x*u0z, n1z=u1x*u0y-u1y*u0x;
    norm3(n2x,n2y,n2z); norm3(n1x,n1y,n1z);
    float cosD = n2x*n1x + n2y*n1y + n2z*n1z;
    const float lo = (float)(-1.0 + 1e-7), hi = (float)(1.0 - 1e-7);
    cosD = fminf(fmaxf(cosD, lo), hi);
    float sg = u2x*n1x + u2y*n1y + u2z*n1z;
    float sgn = (sg > 0.f) ? 1.f : ((sg < 0.f) ? -1.f : 0.f);
    float D = sgn * acosf(cosD);
    cD = cosf(D); sD = sinf(D);
  }
  int n = t/3, col = t - n*3;
  bbe[(size_t)n*104 + col] = cD;
  bbe[(size_t)n*104 + 3 + col] = sD;
}

// ---------------- KNN: wave per query ----------------
// Seed: bitonic-sort the 64-wide index window around n (random-walk locality
// makes this a near-final top-30), then scan all 8192 with the tight
// threshold, skipping the window. Exact: every j considered exactly once.
__global__ __launch_bounds__(256) void k_knn(const float* __restrict__ xs,
        const float* __restrict__ ys, const float* __restrict__ zs, int* __restrict__ src){
  __shared__ float sd[4][32];
  __shared__ int   si[4][32];
  int w = threadIdx.x >> 6, lane = threadIdx.x & 63;
  int n = blockIdx.x*4 + w;
  float qx = xs[n], qy = ys[n], qz = zs[n];
  if (lane >= 30 && lane < 32){ sd[w][lane] = INFINITY; si[w][lane] = 0; }

  // ---- seed from index window [w0, w0+64) ----
  int w0 = n - 32; if (w0 < 0) w0 = 0; if (w0 > NN-64) w0 = NN-64;
  int idx = w0 + lane;
  {
    float dx = qx - xs[idx], dy = qy - ys[idx], dz = qz - zs[idx];
    float d2 = dx*dx + dy*dy + dz*dz;
    if (idx == n) d2 = INFINITY;
    // bitonic sort ascending by (d2, idx) across the wave
    #pragma unroll
    for (int k = 2; k <= 64; k <<= 1){
      #pragma unroll
      for (int jj = k>>1; jj >= 1; jj >>= 1){
        float od = __shfl_xor(d2, jj);
        int   oi = __shfl_xor(idx, jj);
        bool up      = ((lane & k) == 0);
        bool lower   = ((lane & jj) == 0);
        bool takeMin = (up == lower);
        bool mless   = (d2 < od) || (d2 == od && idx < oi);
        if (mless != takeMin){ d2 = od; idx = oi; }
      }
    }
    if (lane < 30){ sd[w][lane] = d2; si[w][lane] = idx; }
  }
  float thr = __shfl(sd[w][29], 0);  // lane-uniform read below anyway
  thr = sd[w][29];

  // ---- full scan with tight threshold ----
  for (int s = 0; s < NN/64; ++s){
    int j = s*64 + lane;
    float dx = __fsub_rn(qx, xs[j]);
    float dy = __fsub_rn(qy, ys[j]);
    float dz = __fsub_rn(qz, zs[j]);
    float d2 = __fadd_rn(__fadd_rn(__fmul_rn(dx,dx),__fmul_rn(dy,dy)),__fmul_rn(dz,dz));
    if (j == n) d2 = INFINITY;
    if (j >= w0 && j < w0+64) d2 = INFINITY;   // already seeded
    unsigned long long bal = __ballot(d2 < thr);
    if (bal){
      while (bal){
        int b = __ffsll((unsigned long long)bal) - 1;
        bal &= bal - 1ull;
        float vd = __shfl(d2, b);
        int vj = s*64 + b;
        float dl = 0.f; int il = 0; bool keep = true;
        if (lane < 30){ dl = sd[w][lane]; il = si[w][lane]; keep = (dl <= vd); }
        unsigned long long km = __ballot(lane < 30 && keep);
        int pos = __popcll(km);
        if (lane < 30 && !keep){ sd[w][lane+1] = dl; si[w][lane+1] = il; }
        if (lane == pos){ sd[w][lane] = vd; si[w][lane] = vj; }
      }
      thr = sd[w][29];
    }
  }
  if (lane < 30) src[(size_t)n*KK + lane] = si[w][lane];
}

// ---------------- edge features: rbf(16) + pos_emb(16) ----------------
__global__ void k_edgefeat(const int* __restrict__ src, const float* __restrict__ xs,
        const float* __restrict__ ys, const float* __restrict__ zs, float* __restrict__ ef){
  int e = blockIdx.x*blockDim.x + threadIdx.x;
  if (e >= NE) return;
  int n = e / KK;
  int j = src[e];
  float vx = xs[j]-xs[n], vy = ys[j]-ys[n], vz = zs[j]-zs[n];
  float dist = sqrtf(vx*vx + vy*vy + vz*vz + EPSF);
  float* o = ef + (size_t)e*32;
  #pragma unroll
  for (int m=0;m<16;++m){
    float mu = (float)m * (20.f/15.f);
    float q = (dist - mu) / 1.25f;
    o[m] = expf(-q*q);
  }
  float d = (float)(j - n);
  const float Cf = -0.5756462732485115f;   // -ln(1e4)/16
  #pragma unroll
  for (int fi=0; fi<8; ++fi){
    float fr = expf((float)(2*fi) * Cf);
    float ang = d * fr;
    o[16+fi] = cosf(ang);
    o[24+fi] = sinf(ang);
  }
}

// ---------------- generic f32 GEMM: C[M,Nc] = act(A@B + bias) (+C if beta) ----------------
// A row r -> A + (r/arpg)*agst + (r%arpg)*arst + aoff  (arpg in {1,3})
template<int K, int ACT>
__global__ __launch_bounds__(256) void k_gemm(const float* __restrict__ A,
        const float* __restrict__ B, const float* __restrict__ bias, float* __restrict__ C,
        int M, int Nc, int arpg, int agst, int arst, int aoff, int beta){
  __shared__ float As[64*(K+1)];
  __shared__ alignas(16) float Bs[K*64];
  int tid = threadIdx.x, tm = blockIdx.x, tn = blockIdx.y;
  for (int i = tid; i < K*64; i += 256){
    int kk = i >> 6, cl = i & 63;
    int c = tn*64 + cl;
    Bs[i] = (c < Nc) ? B[kk*Nc + c] : 0.f;
  }
  for (int i = tid; i < 64*K; i += 256){
    int rl = i / K, kk = i - rl*K;
    int r = tm*64 + rl;
    float v = 0.f;
    if (r < M){
      const float* ap;
      if (arpg == 1) ap = A + (size_t)r*agst + aoff;
      else { int g = r/3; int wr = r - g*3; ap = A + (size_t)g*agst + wr*arst + aoff; }
      v = ap[kk];
    }
    As[rl*(K+1) + kk] = v;
  }
  __syncthreads();
  int tx = tid & 15, ty = tid >> 4;
  float acc[4][4] = {};
  for (int kk = 0; kk < K; ++kk){
    float4 b4 = *reinterpret_cast<const float4*>(&Bs[kk*64 + tx*4]);
    #pragma unroll
    for (int rr = 0; rr < 4; ++rr){
      float a = As[(ty*4+rr)*(K+1) + kk];
      acc[rr][0] += a*b4.x; acc[rr][1] += a*b4.y; acc[rr][2] += a*b4.z; acc[rr][3] += a*b4.w;
    }
  }
  #pragma unroll
  for (int rr = 0; rr < 4; ++rr){
    int r = tm*64 + ty*4 + rr;
    if (r >= M) continue;
    #pragma unroll
    for (int cc = 0; cc < 4; ++cc){
      int c = tn*64 + tx*4 + cc;
      if (c >= Nc) continue;
      float v = acc[rr][cc];
      if (bias) v += bias[c];
      if (ACT == 1) v = v / (1.f + expf(-v)) ;   // silu = x*sigmoid(x) = x/(1+e^-x)
      size_t ci = (size_t)r*Nc + c;
      if (beta) v += C[ci];
      C[ci] = v;
    }
  }
}

// ---------------- fused attention: logits+softmax+gather-weighted sums ----------------
// NF: [A1(8)|A2(8)|V0(64)] per node; V1: (N,3,64); LG: per-edge logit partial (stride lgs)
__global__ __launch_bounds__(256) void k_attn(const int* __restrict__ src,
        const float* __restrict__ NF, const float* __restrict__ V1,
        const float* __restrict__ LG, int lgs, float* __restrict__ o){
  int w = threadIdx.x >> 6, lane = threadIdx.x & 63;
  int n = blockIdx.x*4 + w;
  int h = lane >> 3;
  const int* sk = src + (size_t)n*KK;
  int myj = (lane < KK) ? sk[lane] : 0;
  float a2 = NF[(size_t)n*80 + 8 + h];
  float m = -INFINITY, s = 0.f, o0=0.f, o1=0.f, o2=0.f, o3=0.f;
  for (int k = 0; k < KK; ++k){
    int j = __shfl(myj, k);
    float l = LG[((size_t)n*KK + k)*lgs + h] + NF[(size_t)j*80 + h] + a2;
    l = (l >= 0.f) ? l : 0.2f*l;
    float mn = fmaxf(m, l);
    float f = expf(m - mn);
    float pp = expf(l - mn);
    s = s*f + pp;
    const float* v1p = V1 + (size_t)j*192;
    o0 = o0*f + pp*NF[(size_t)j*80 + 16 + lane];
    o1 = o1*f + pp*v1p[lane];
    o2 = o2*f + pp*v1p[64+lane];
    o3 = o3*f + pp*v1p[128+lane];
    m = mn;
  }
  float inv = 1.f/s;
  float* op = o + (size_t)n*256;
  op[lane] = o0*inv; op[64+lane] = o1*inv; op[128+lane] = o2*inv; op[192+lane] = o3*inv;
}

// ---------------- so3 gather-aggregate ----------------
template<int C>
__global__ void k_so3agg(const int* __restrict__ src, const float* __restrict__ G,
        const float* __restrict__ M0, const float* __restrict__ M1, float* __restrict__ out,
        int n0, int nodes, int nstr, int sstr){
  int t = blockIdx.x*blockDim.x + threadIdx.x;
  if (t >= nodes*C) return;
  int nl = t / C, c = t - nl*C;
  int n = n0 + nl;
  const int* sk = src + (size_t)n*KK;
  const float* gb = G + (size_t)nl*KK*2*C;
  float a0=0.f,a1=0.f,a2=0.f,a3=0.f;
  for (int k=0;k<KK;++k){
    int j = sk[k];
    float g0 = gb[k*2*C + c], g1 = gb[k*2*C + C + c];
    a0 += g0 * M0[(size_t)j*C + c];
    const float* m1p = M1 + (size_t)j*3*C;
    a1 += g1*m1p[c]; a2 += g1*m1p[C+c]; a3 += g1*m1p[2*C+c];
  }
  const float SQ = 5.477225575051661f;  // sqrt(30)
  float* ob = out + (size_t)n*nstr + c;
  ob[0] = a0/SQ; ob[sstr] = a1/SQ; ob[2*sstr] = a2/SQ; ob[3*sstr] = a3/SQ;
}

// ---------------- latent copy into res cols 32..63 ----------------
__global__ void k_lat(const float* __restrict__ latent, float* __restrict__ res){
  int t = blockIdx.x*blockDim.x + threadIdx.x;
  if (t >= NN*128) return;
  int n = t >> 7, rc = t & 127, s = rc >> 5, c = rc & 31;
  res[(size_t)n*256 + s*64 + 32 + c] = latent[t];
}

// ---------------- swiglu-style FFN gate ----------------
template<int C>
__global__ void k_swiglu(const float* __restrict__ T, float* __restrict__ U){
  int t = blockIdx.x*blockDim.x + threadIdx.x;
  if (t >= NN*C) return;
  int n = t / C, c = t - n*C;
  const float* tp = T + (size_t)n*4*C + c;
  float t0 = tp[0];
  float g = 1.f/(1.f + expf(-t0));
  float* up = U + (size_t)n*4*C + c;
  up[0]   = t0*g;
  up[C]   = tp[C]*g;
  up[2*C] = tp[2*C]*g;
  up[3*C] = tp[3*C]*g;
}

// ---------------- edge feature update ----------------
__global__ void k_edgeout(const int* __restrict__ src, const float* __restrict__ EW,
        const float* __restrict__ EE, const float* __restrict__ ebv, float* __restrict__ ef){
  int t = blockIdx.x*blockDim.x + threadIdx.x;
  if (t >= NE*8) return;
  int e = t >> 3, q = t & 7, c = q*4;
  int n = e / KK;
  int j = src[e];
  float4 w4 = *(const float4*)(EW + (size_t)e*40 + 8 + c);
  float4 e1 = *(const float4*)(EE + (size_t)j*64 + c);
  float4 e2 = *(const float4*)(EE + (size_t)n*64 + 32 + c);
  float4 b4 = *(const float4*)(ebv + c);
  float4 r;
  r.x = tanhf(w4.x + e1.x + e2.x + b4.x);
  r.y = tanhf(w4.y + e1.y + e2.y + b4.y);
  r.z = tanhf(w4.z + e1.z + e2.z + b4.z);
  r.w = tanhf(w4.w + e1.w + e2.w + b4.w);
  *(float4*)(ef + (size_t)e*32 + c) = r;
}

// ---------------- per-layer weight repack ----------------
// Bnode(64,80)=[Wa_src|Wa_dst|Wv0], Bedge(32,40)=[Wa_e|eW_e], Bee(64,64)=[eW_src|eW_dst]
__global__ void k_repack(const float* __restrict__ Wa, const float* __restrict__ Wv0,
        const float* __restrict__ eW, float* __restrict__ Bnode, float* __restrict__ Bedge,
        float* __restrict__ Bee){
  int t = blockIdx.x*blockDim.x + threadIdx.x;
  if (t < 5120){
    int k = t/80, c = t - k*80;
    Bnode[t] = (c<8) ? Wa[k*8+c] : ((c<16) ? Wa[(64+k)*8 + (c-8)] : Wv0[k*64 + (c-16)]);
  } else if (t < 6400){
    int i = t - 5120; int k = i/40, c = i - k*40;
    Bedge[i] = (c<8) ? Wa[(128+k)*8 + c] : eW[(128+k)*32 + (c-8)];
  } else if (t < 10496){
    int i = t - 6400; int k = i >> 6, c = i & 63;
    Bee[i] = (c<32) ? eW[k*32 + c] : eW[(64+k)*32 + (c-32)];
  }
}

// ---------------- head: LN + seq logits + transpose decoded ----------------
__global__ __launch_bounds__(128) void k_head(const float* __restrict__ atoms,
        const float* __restrict__ ln_g, const float* __restrict__ ln_b,
        const float* __restrict__ W_seq, const float* __restrict__ b_seq, float* __restrict__ out){
  __shared__ float red[128];
  __shared__ float nrm[91];
  __shared__ float lg[20];
  int n = blockIdx.x, t = threadIdx.x;
  const float* inv = atoms + (size_t)n*364;
  float x = (t < 91) ? inv[t] : 0.f;
  red[t] = x; __syncthreads();
  for (int off=64; off>=1; off>>=1){ if (t<off) red[t]+=red[t+off]; __syncthreads(); }
  float mu = red[0] / 91.f;
  __syncthreads();
  float d = x - mu;
  red[t] = (t<91) ? d*d : 0.f; __syncthreads();
  for (int off=64; off>=1; off>>=1){ if (t<off) red[t]+=red[t+off]; __syncthreads(); }
  float var = red[0] / 91.f;
  __syncthreads();
  if (t < 91) nrm[t] = (x - mu)/sqrtf(var + 1e-5f) * ln_g[t] + ln_b[t];
  __syncthreads();
  if (t < 20){
    float acc = b_seq[t];
    for (int c=0;c<91;++c) acc += nrm[c]*W_seq[c*20+t];
    lg[t] = acc;
  }
  __syncthreads();
  if (t == 0){
    float mx = lg[0];
    for (int i=1;i<20;++i) mx = fmaxf(mx, lg[i]);
    float s = 0.f;
    for (int i=0;i<20;++i) s += expf(lg[i]-mx);
    red[0] = mx + logf(s);
  }
  __syncthreads();
  float lse = red[0];
  if (t < 20) out[(size_t)NN*273 + (size_t)n*20 + t] = lg[t] - lse;
  for (int idx = t; idx < 273; idx += 128){
    int c = idx/3, i = idx - c*3;
    out[(size_t)n*273 + idx] = atoms[(size_t)n*364 + (1+i)*91 + c];
  }
}

// ---------------- host dispatch ----------------
static void gemm(hipStream_t st, int K, int act, const float* A, const float* B,
                 const float* bias, float* C, int M, int Nc,
                 int arpg, int agst, int arst, int aoff, int beta){
  dim3 g((M+63)/64, (Nc+63)/64), b(256);
  if (K == 26){
    k_gemm<26,0><<<g,b,0,st>>>(A,B,bias,C,M,Nc,arpg,agst,arst,aoff,beta);
  } else if (K == 32){
    if (act) k_gemm<32,1><<<g,b,0,st>>>(A,B,bias,C,M,Nc,arpg,agst,arst,aoff,beta);
    else     k_gemm<32,0><<<g,b,0,st>>>(A,B,bias,C,M,Nc,arpg,agst,arst,aoff,beta);
  } else {
    if (act) k_gemm<64,1><<<g,b,0,st>>>(A,B,bias,C,M,Nc,arpg,agst,arst,aoff,beta);
    else     k_gemm<64,0><<<g,b,0,st>>>(A,B,bias,C,M,Nc,arpg,agst,arst,aoff,beta);
  }
}

extern "C" void kernel_launch(void* const* d_in, const int* in_sizes, int n_in,
                              void* d_out, int out_size, void* d_ws, size_t ws_size,
                              hipStream_t stream){
  (void)in_sizes; (void)n_in; (void)out_size;
  if (ws_size < WS_NEEDED) return;  // insufficient scratch: leave d_out poisoned (fails cleanly)

  const float* bb      = (const float*)d_in[0];
  const float* latent  = (const float*)d_in[2];
  const float* eb_Wrad = (const float*)d_in[3];
  const float* eb_brad = (const float*)d_in[4];
  const float* eb_Wgate= (const float*)d_in[5];
  const float* eb_W0   = (const float*)d_in[6];
  const float* eb_W1   = (const float*)d_in[7];
  const float* t_Walpha= (const float*)d_in[8];
  const float* t_Wv0   = (const float*)d_in[9];
  const float* t_Wv1   = (const float*)d_in[10];
  const float* t_Wo    = (const float*)d_in[11];
  const float* t_Wf1   = (const float*)d_in[12];
  const float* t_Wf2   = (const float*)d_in[13];
  const float* e_W     = (const float*)d_in[14];
  const float* e_b     = (const float*)d_in[15];
  const float* p_Walpha= (const float*)d_in[16];
  const float* p_Wv0   = (const float*)d_in[17];
  const float* p_Wv1   = (const float*)d_in[18];
  const float* p_Wo    = (const float*)d_in[19];
  const float* p_Wf1   = (const float*)d_in[20];
  const float* p_Wf2   = (const float*)d_in[21];
  const float* oa_Wrad = (const float*)d_in[22];
  const float* oa_brad = (const float*)d_in[23];
  const float* oa_Wgate= (const float*)d_in[24];
  const float* oa_W0   = (const float*)d_in[25];
  const float* oa_W1   = (const float*)d_in[26];
  const float* ln_g    = (const float*)d_in[27];
  const float* ln_b    = (const float*)d_in[28];
  const float* W_seq   = (const float*)d_in[29];
  const float* b_seq   = (const float*)d_in[30];

  char* w = (char*)d_ws;
  int*   src = (int*)  (w + O_SRC);
  float* xs  = (float*)(w + O_XS);
  float* ys  = (float*)(w + O_YS);
  float* zs  = (float*)(w + O_ZS);
  float* bbe = (float*)(w + O_BBE);
  float* res = (float*)(w + O_RES);
  float* p   = (float*)(w + O_P);
  float* ef  = (float*)(w + O_EF);
  float* NF  = (float*)(w + O_NF);
  float* V1  = (float*)(w + O_V1);
  float* o   = (float*)(w + O_O);
  float* T   = (float*)(w + O_T);
  float* EE  = (float*)(w + O_EE);
  float* EW  = (float*)(w + O_EW);
  float* M0  = (float*)(w + O_M0);
  float* M1  = (float*)(w + O_M1);
  float* atm = (float*)(w + O_ATM);
  float* H   = (float*)(w + O_H);
  float* G   = (float*)(w + O_G);
  float* Bnode = (float*)(w + O_BRP);
  float* Bedge = (float*)(w + O_BRP + 32768);
  float* Bee   = (float*)(w + O_BRP + 65536);

  // ---- geometry ----
  k_prep <<<(NN+255)/256, 256, 0, stream>>>(bb, xs, ys, zs, bbe);
  k_dihed<<<(3*NN+255)/256, 256, 0, stream>>>(bb, bbe);
  k_knn  <<<NN/4, 256, 0, stream>>>(xs, ys, zs, src);
  k_edgefeat<<<(NE+255)/256, 256, 0, stream>>>(src, xs, ys, zs, ef);

  // ---- eb so3_conv -> res[:,:,0:32] ----
  gemm(stream, 26,0, bbe, eb_W0, nullptr, M0, NN,   32, 1,104, 0, 0, 0);
  gemm(stream, 26,0, bbe, eb_W1, nullptr, M1, 3*NN, 32, 3,104,26,26, 0);
  for (int cz=0; cz<4; ++cz){
    int n0 = cz*2048, me = 2048*KK;
    gemm(stream, 32,1, ef + (size_t)n0*KK*32, eb_Wrad, eb_brad, H, me, 64, 1,32,0,0, 0);
    gemm(stream, 64,0, H, eb_Wgate, nullptr, G, me, 64, 1,64,0,0, 0);
    k_so3agg<32><<<(2048*32+255)/256, 256, 0, stream>>>(src, G, M0, M1, res, n0, 2048, 256, 64);
  }
  k_lat<<<(NN*128+255)/256, 256, 0, stream>>>(latent, res);

  // ---- transformer layers ----
  for (int L=0; L<4; ++L){
    const float* Wa  = t_Walpha + (size_t)L*160*8;
    const float* Wv0 = t_Wv0 + (size_t)L*64*64;
    const float* Wv1 = t_Wv1 + (size_t)L*64*64;
    const float* Wo  = t_Wo  + (size_t)L*64*64;
    const float* Wf1 = t_Wf1 + (size_t)L*64*64;
    const float* Wf2 = t_Wf2 + (size_t)L*64*64;
    const float* eWl = e_W   + (size_t)L*160*32;
    const float* ebl = e_b   + (size_t)L*32;
    k_repack<<<41, 256, 0, stream>>>(Wa, Wv0, eWl, Bnode, Bedge, Bee);
    gemm(stream, 64,0, res, Bnode, nullptr, NF, NN,   80, 1,256, 0, 0, 0);
    gemm(stream, 64,0, res, Wv1,   nullptr, V1, 3*NN, 64, 3,256,64,64, 0);
    gemm(stream, 32,0, ef,  Bedge, nullptr, EW, NE,   40, 1, 32, 0, 0, 0);
    k_attn<<<NN/4, 256, 0, stream>>>(src, NF, V1, EW, 40, o);
    gemm(stream, 64,0, o,   Wo,  nullptr, res, 4*NN, 64, 1,64,0,0, 1);
    gemm(stream, 64,0, res, Wf1, nullptr, T,   4*NN, 64, 1,64,0,0, 0);
    k_swiglu<64><<<(NN*64+255)/256, 256, 0, stream>>>(T, o);
    gemm(stream, 64,0, o,   Wf2, nullptr, res, 4*NN, 64, 1,64,0,0, 1);
    gemm(stream, 64,0, res, Bee, nullptr, EE,  NN,   64, 1,256,0,0, 0);
    k_edgeout<<<(NE*8+255)/256, 256, 0, stream>>>(src, EW, EE, ebl, ef);
  }

  // ---- p = attn(res) + ffn ----
  k_repack<<<41, 256, 0, stream>>>(p_Walpha, p_Wv0, e_W + (size_t)3*160*32, Bnode, Bedge, Bee);
  gemm(stream, 64,0, res, Bnode, nullptr, NF, NN,   80, 1,256, 0, 0, 0);
  gemm(stream, 64,0, res, p_Wv1, nullptr, V1, 3*NN, 64, 3,256,64,64, 0);
  gemm(stream, 32,0, ef,  p_Walpha + 128*8, nullptr, EW, NE, 8, 1,32,0,0, 0);
  k_attn<<<NN/4, 256, 0, stream>>>(src, NF, V1, EW, 8, o);
  gemm(stream, 64,0, o, p_Wo,  nullptr, p, 4*NN, 32, 1,64,0,0, 0);
  gemm(stream, 32,0, p, p_Wf1, nullptr, T, 4*NN, 32, 1,32,0,0, 0);
  k_swiglu<32><<<(NN*32+255)/256, 256, 0, stream>>>(T, o);
  gemm(stream, 32,0, o, p_Wf2, nullptr, p, 4*NN, 32, 1,32,0,0, 1);

  // ---- oa so3_conv -> atoms ----
  gemm(stream, 32,0, p, oa_W0, nullptr, M0, NN,   91, 1,128, 0, 0, 0);
  gemm(stream, 32,0, p, oa_W1, nullptr, M1, 3*NN, 91, 3,128,32,32, 0);
  for (int cz=0; cz<4; ++cz){
    int n0 = cz*2048, me = 2048*KK;
    gemm(stream, 32,1, ef + (size_t)n0*KK*32, oa_Wrad, oa_brad, H, me, 64, 1,32,0,0, 0);
    gemm(stream, 64,0, H, oa_Wgate, nullptr, G, me, 182, 1,64,0,0, 0);
    k_so3agg<91><<<(2048*91+255)/256, 256, 0, stream>>>(src, G, M0, M1, atm, n0, 2048, 364, 91);
  }

  // ---- head ----
  k_head<<<NN, 128, 0, stream>>>(atm, ln_g, ln_b, W_seq, b_seq, (float*)d_out);
}